// Round 1
// baseline (312.815 us; speedup 1.0000x reference)
//
#include <hip/hip_runtime.h>
#include <hip/hip_bf16.h>
#include <cstdint>

typedef __hip_bfloat16 bf16;
typedef __attribute__((ext_vector_type(8))) short bf16x8;
typedef __attribute__((ext_vector_type(4))) float f32x4;

#define T_SEQ 2048
#define DMODEL 1024
#define NHEAD 16
#define DHEAD 64
#define MROWS 4096

typedef const __attribute__((address_space(1))) void* gas_ptr;
typedef __attribute__((address_space(3))) void* las_ptr;

static __device__ __forceinline__ f32x4 mfma16(bf16x8 a, bf16x8 b, f32x4 c) {
  return __builtin_amdgcn_mfma_f32_16x16x32_bf16(a, b, c, 0, 0, 0);
}
static __device__ __forceinline__ void gload_lds16(const void* g, void* l) {
  __builtin_amdgcn_global_load_lds((gas_ptr)g, (las_ptr)l, 16, 0, 0);
}
static __device__ __forceinline__ float b2f(unsigned short u) {
  union { unsigned int i; float f; } x; x.i = ((unsigned int)u) << 16; return x.f;
}
static __device__ __forceinline__ unsigned short f2bu(float f) {
  __hip_bfloat16 h = __float2bfloat16(f);
  unsigned short u; __builtin_memcpy(&u, &h, 2); return u;
}

// ---------------- weight fp32 -> bf16 ----------------
__global__ void f2b_k(const float* __restrict__ in, bf16* __restrict__ out, int n) {
  int idx = (blockIdx.x * blockDim.x + threadIdx.x) * 4;
  if (idx < n) {
    float4 v = *(const float4*)(in + idx);
    out[idx]     = __float2bfloat16(v.x);
    out[idx + 1] = __float2bfloat16(v.y);
    out[idx + 2] = __float2bfloat16(v.z);
    out[idx + 3] = __float2bfloat16(v.w);
  }
}

// ---------------- RMSNorm: fp32 in -> bf16 out ----------------
__global__ __launch_bounds__(256) void rms_k(const float* __restrict__ x,
                                             const float* __restrict__ w,
                                             bf16* __restrict__ out) {
  const int row = blockIdx.x;
  const int tid = threadIdx.x;
  const float4 v = ((const float4*)(x + (size_t)row * DMODEL))[tid];
  float ss = v.x * v.x + v.y * v.y + v.z * v.z + v.w * v.w;
#pragma unroll
  for (int off = 32; off; off >>= 1) ss += __shfl_xor(ss, off);
  __shared__ float red[4];
  if ((tid & 63) == 0) red[tid >> 6] = ss;
  __syncthreads();
  const float tot = red[0] + red[1] + red[2] + red[3];
  const float rinv = rsqrtf(tot * (1.f / DMODEL) + 1e-6f);
  const float4 wv = ((const float4*)w)[tid];
  bf16* o = out + (size_t)row * DMODEL + tid * 4;
  o[0] = __float2bfloat16(v.x * rinv * wv.x);
  o[1] = __float2bfloat16(v.y * rinv * wv.y);
  o[2] = __float2bfloat16(v.z * rinv * wv.z);
  o[3] = __float2bfloat16(v.w * rinv * wv.w);
}

// ---------------- GEMM: C = A(M,K) x Bw(N,K)^T, bf16 in, fp32 accum ----------------
// m97 structure: 128x128 tile, BK=32, 4 waves (each 64x64 = 4x4 frags of 16x16x32),
// global_load_lds width=16, single LDS buffer, 2 barriers per K-step.
// EPI: 0 = bf16 store to o0 (ld=N); 1 = qkv scatter to o0/o1/o2 as (B,H,T,64);
//      2 = fp32 store o0 = res + C (ld=N)
template <int K, int EPI>
__global__ __launch_bounds__(256) void gemm_bt(const bf16* __restrict__ A,
                                               const bf16* __restrict__ Bw, int N,
                                               void* __restrict__ o0, void* __restrict__ o1,
                                               void* __restrict__ o2,
                                               const float* __restrict__ res) {
  __shared__ bf16 As[128 * 32];
  __shared__ bf16 Bs[128 * 32];
  const int bn0 = blockIdx.x * 128;
  const int bm0 = blockIdx.y * 128;
  const int tid = threadIdx.x;
  const int wave = tid >> 6, lane = tid & 63;
  const int wr = wave >> 1, wc = wave & 1;
  const int fr = lane & 15, g8 = (lane >> 4) * 8, r4 = (lane >> 4) * 4;
  const int srow = lane >> 2;
  const int scol = (lane & 3) * 8;

  const f32x4 fzero = {0.f, 0.f, 0.f, 0.f};
  f32x4 acc[4][4];
#pragma unroll
  for (int i = 0; i < 4; i++)
#pragma unroll
    for (int j = 0; j < 4; j++) acc[i][j] = fzero;

  const bf16* gA0 = A + (size_t)(bm0 + wave * 16 + srow) * K + scol;
  const bf16* gA1 = A + (size_t)(bm0 + (wave + 4) * 16 + srow) * K + scol;
  const bf16* gB0 = Bw + (size_t)(bn0 + wave * 16 + srow) * K + scol;
  const bf16* gB1 = Bw + (size_t)(bn0 + (wave + 4) * 16 + srow) * K + scol;

  for (int k0 = 0; k0 < K; k0 += 32) {
    gload_lds16(gA0 + k0, &As[wave * 512]);
    gload_lds16(gA1 + k0, &As[(wave + 4) * 512]);
    gload_lds16(gB0 + k0, &Bs[wave * 512]);
    gload_lds16(gB1 + k0, &Bs[(wave + 4) * 512]);
    __syncthreads();
    bf16x8 af[4], bfr[4];
#pragma unroll
    for (int mr = 0; mr < 4; mr++)
      af[mr] = *(const bf16x8*)&As[(wr * 64 + mr * 16 + fr) * 32 + g8];
#pragma unroll
    for (int nr = 0; nr < 4; nr++)
      bfr[nr] = *(const bf16x8*)&Bs[(wc * 64 + nr * 16 + fr) * 32 + g8];
#pragma unroll
    for (int mr = 0; mr < 4; mr++)
#pragma unroll
      for (int nr = 0; nr < 4; nr++)
        acc[mr][nr] = mfma16(af[mr], bfr[nr], acc[mr][nr]);
    __syncthreads();
  }

#pragma unroll
  for (int mr = 0; mr < 4; mr++) {
#pragma unroll
    for (int nr = 0; nr < 4; nr++) {
#pragma unroll
      for (int r = 0; r < 4; r++) {
        const int row = bm0 + wr * 64 + mr * 16 + r4 + r;
        const int col = bn0 + wc * 64 + nr * 16 + fr;
        const float vsum = acc[mr][nr][r];
        if (EPI == 0) {
          ((bf16*)o0)[(size_t)row * N + col] = __float2bfloat16(vsum);
        } else if (EPI == 1) {
          const int sel = col >> 10;
          const int n = col & 1023;
          const int h = n >> 6, d = n & 63;
          const int b = row >> 11, t = row & 2047;
          bf16* dst = (sel == 0) ? (bf16*)o0 : ((sel == 1) ? (bf16*)o1 : (bf16*)o2);
          dst[(((size_t)(b * NHEAD + h)) * T_SEQ + t) * DHEAD + d] = __float2bfloat16(vsum);
        } else {
          ((float*)o0)[(size_t)row * N + col] = res[(size_t)row * N + col] + vsum;
        }
      }
    }
  }
}

// ---------------- causal flash attention ----------------
// grid (32 bh, 32 qblk64), 256 thr = 4 waves; wave handles 16 Q rows.
// q/k/v layout (B,H,T,64) bf16. y written as (B,T,H,64) bf16.
__global__ __launch_bounds__(256) void attn_k(const bf16* __restrict__ qb,
                                              const bf16* __restrict__ kb,
                                              const bf16* __restrict__ vb,
                                              bf16* __restrict__ y) {
  const int bh = blockIdx.x;
  const int wave = threadIdx.x >> 6, lane = threadIdx.x & 63;
  const int q0 = blockIdx.y * 64 + wave * 16;
  const int b = bh >> 4, h = bh & 15;
  const int fr = lane & 15, g8 = (lane >> 4) * 8, r4 = (lane >> 4) * 4;

  const bf16* qp = qb + (size_t)bh * T_SEQ * DHEAD;
  const bf16* kp = kb + (size_t)bh * T_SEQ * DHEAD;
  const short* vps = (const short*)(vb + (size_t)bh * T_SEQ * DHEAD);

  const bf16x8 qf0 = *(const bf16x8*)(qp + (size_t)(q0 + fr) * DHEAD + g8);
  const bf16x8 qf1 = *(const bf16x8*)(qp + (size_t)(q0 + fr) * DHEAD + 32 + g8);

  const f32x4 fzero = {0.f, 0.f, 0.f, 0.f};
  float m[4], lsum[4];
  f32x4 acc[4];
#pragma unroll
  for (int r = 0; r < 4; r++) { m[r] = -1e30f; lsum[r] = 0.f; }
#pragma unroll
  for (int nf = 0; nf < 4; nf++) acc[nf] = fzero;

  __shared__ bf16 pl[4][16][32];
  bf16(*plw)[32] = pl[wave];

  const int kend = q0 + 16;
  for (int kt = 0; kt < kend; kt += 32) {
    f32x4 s0 = fzero, s1 = fzero;
    {
      int kr0 = kt + fr;      if (kr0 > T_SEQ - 1) kr0 = T_SEQ - 1;
      int kr1 = kt + 16 + fr; if (kr1 > T_SEQ - 1) kr1 = T_SEQ - 1;
      bf16x8 kf;
      kf = *(const bf16x8*)(kp + (size_t)kr0 * DHEAD + g8);      s0 = mfma16(qf0, kf, s0);
      kf = *(const bf16x8*)(kp + (size_t)kr0 * DHEAD + 32 + g8); s0 = mfma16(qf1, kf, s0);
      kf = *(const bf16x8*)(kp + (size_t)kr1 * DHEAD + g8);      s1 = mfma16(qf0, kf, s1);
      kf = *(const bf16x8*)(kp + (size_t)kr1 * DHEAD + 32 + g8); s1 = mfma16(qf1, kf, s1);
    }
    float p0[4], p1[4], ef[4];
#pragma unroll
    for (int r = 0; r < 4; r++) {
      const int qrow = q0 + r4 + r;
      float a0 = (kt + fr <= qrow) ? s0[r] * 0.125f : -1e30f;
      float a1 = (kt + 16 + fr <= qrow) ? s1[r] * 0.125f : -1e30f;
      float tm = fmaxf(a0, a1);
      tm = fmaxf(tm, __shfl_xor(tm, 1));
      tm = fmaxf(tm, __shfl_xor(tm, 2));
      tm = fmaxf(tm, __shfl_xor(tm, 4));
      tm = fmaxf(tm, __shfl_xor(tm, 8));
      const float mn = fmaxf(m[r], tm);
      const float e = __expf(m[r] - mn);
      ef[r] = e;
      m[r] = mn;
      const float x0 = __expf(a0 - mn), x1 = __expf(a1 - mn);
      p0[r] = x0; p1[r] = x1;
      float rs = x0 + x1;
      rs += __shfl_xor(rs, 1);
      rs += __shfl_xor(rs, 2);
      rs += __shfl_xor(rs, 4);
      rs += __shfl_xor(rs, 8);
      lsum[r] = lsum[r] * e + rs;
    }
#pragma unroll
    for (int nf = 0; nf < 4; nf++)
#pragma unroll
      for (int r = 0; r < 4; r++) acc[nf][r] *= ef[r];
#pragma unroll
    for (int r = 0; r < 4; r++) {
      plw[r4 + r][fr] = __float2bfloat16(p0[r]);
      plw[r4 + r][16 + fr] = __float2bfloat16(p1[r]);
    }
    const bf16x8 pa = *(const bf16x8*)&plw[fr][g8];
#pragma unroll
    for (int nf = 0; nf < 4; nf++) {
      bf16x8 vf;
#pragma unroll
      for (int j = 0; j < 8; j++) {
        int vr = kt + g8 + j; if (vr > T_SEQ - 1) vr = T_SEQ - 1;
        vf[j] = vps[(size_t)vr * DHEAD + nf * 16 + fr];
      }
      acc[nf] = mfma16(pa, vf, acc[nf]);
    }
  }

#pragma unroll
  for (int r = 0; r < 4; r++) {
    const float inv = 1.f / lsum[r];
    const int t = q0 + r4 + r;
#pragma unroll
    for (int nf = 0; nf < 4; nf++) {
      const int d = nf * 16 + fr;
      y[(((size_t)(b * T_SEQ + t)) * NHEAD + h) * DHEAD + d] = __float2bfloat16(acc[nf][r] * inv);
    }
  }
}

// ---------------- gu = silu(g) * u (bf16, in-place into g allowed) ----------------
__global__ void silumul_k(const bf16* __restrict__ g, const bf16* __restrict__ u,
                          bf16* __restrict__ o, int n) {
  const int idx = (blockIdx.x * blockDim.x + threadIdx.x) * 4;
  if (idx < n) {
    const ushort4 gv = *(const ushort4*)((const unsigned short*)g + idx);
    const ushort4 uv = *(const ushort4*)((const unsigned short*)u + idx);
    ushort4 ov;
    float a, s;
    a = b2f(gv.x); s = a / (1.f + __expf(-a)); ov.x = f2bu(s * b2f(uv.x));
    a = b2f(gv.y); s = a / (1.f + __expf(-a)); ov.y = f2bu(s * b2f(uv.y));
    a = b2f(gv.z); s = a / (1.f + __expf(-a)); ov.z = f2bu(s * b2f(uv.z));
    a = b2f(gv.w); s = a / (1.f + __expf(-a)); ov.w = f2bu(s * b2f(uv.w));
    *(ushort4*)((unsigned short*)o + idx) = ov;
  }
}

// ---------------- launch ----------------
extern "C" void kernel_launch(void* const* d_in, const int* in_sizes, int n_in,
                              void* d_out, int out_size, void* d_ws, size_t ws_size,
                              hipStream_t stream) {
  const float* x     = (const float*)d_in[0];
  const float* ln1w  = (const float*)d_in[1];
  const float* ln2w  = (const float*)d_in[2];
  const float* qkvw  = (const float*)d_in[3];
  const float* ow    = (const float*)d_in[4];
  const float* gatew = (const float*)d_in[5];
  const float* upw   = (const float*)d_in[6];
  const float* downw = (const float*)d_in[7];

  uint8_t* ws = (uint8_t*)d_ws;
  // workspace layout (bytes); ~76 MB total with aliasing
  bf16* WQKV = (bf16*)(ws + 0);          // 6291456
  bf16* WO   = (bf16*)(ws + 6291456);    // 2097152
  bf16* WG   = (bf16*)(ws + 8388608);    // 4194304
  bf16* WU   = (bf16*)(ws + 12582912);   // 4194304
  bf16* WD   = (bf16*)(ws + 16777216);   // 4194304
  bf16* H    = (bf16*)(ws + 20971520);   // 8388608
  bf16* Q    = (bf16*)(ws + 29360128);   // 8388608
  bf16* Kb   = (bf16*)(ws + 37748736);   // 8388608
  bf16* V    = (bf16*)(ws + 46137344);   // 8388608
  bf16* Y    = (bf16*)(ws + 54525952);   // 8388608
  float* X2  = (float*)(ws + 62914560);  // 16777216 -> end 79691776
  bf16* G = Q;  // alias over Q+Kb (dead after attention)
  bf16* U = V;  // alias over V+Y  (dead after o-proj)

  // weights -> bf16
  f2b_k<<<3072, 256, 0, stream>>>(qkvw, WQKV, 3072 * 1024);
  f2b_k<<<1024, 256, 0, stream>>>(ow, WO, 1024 * 1024);
  f2b_k<<<2048, 256, 0, stream>>>(gatew, WG, 2048 * 1024);
  f2b_k<<<2048, 256, 0, stream>>>(upw, WU, 2048 * 1024);
  f2b_k<<<2048, 256, 0, stream>>>(downw, WD, 1024 * 2048);

  // attn path
  rms_k<<<MROWS, 256, 0, stream>>>(x, ln1w, H);
  gemm_bt<1024, 1><<<dim3(24, 32), 256, 0, stream>>>(H, WQKV, 3072, Q, Kb, V, nullptr);
  attn_k<<<dim3(32, 32), 256, 0, stream>>>(Q, Kb, V, Y);
  gemm_bt<1024, 2><<<dim3(8, 32), 256, 0, stream>>>(Y, WO, 1024, X2, nullptr, nullptr, x);

  // ffn path
  rms_k<<<MROWS, 256, 0, stream>>>(X2, ln2w, H);
  gemm_bt<1024, 0><<<dim3(16, 32), 256, 0, stream>>>(H, WG, 2048, G, nullptr, nullptr, nullptr);
  gemm_bt<1024, 0><<<dim3(16, 32), 256, 0, stream>>>(H, WU, 2048, U, nullptr, nullptr, nullptr);
  silumul_k<<<8192, 256, 0, stream>>>(G, U, G, 4096 * 2048);
  gemm_bt<2048, 2><<<dim3(8, 32), 256, 0, stream>>>(G, WD, 1024, (float*)d_out, nullptr, nullptr, X2);
}